// Round 6
// baseline (402.865 us; speedup 1.0000x reference)
//
#include <hip/hip_runtime.h>
#include <float.h>

#define FEAT 512
#define TOPK 5
#define NSEL 16
#define ABLK 512                       // attrs per block
#define IBLK 64                        // imgs per block
#define BKT 64                         // K elems (bytes, i8) per tile
#define NKT (FEAT / BKT)               // 8
#define A_BYTES (ABLK * BKT)           // 32768
#define B_BYTES (IBLK * BKT)           // 4096
#define BUF_BYTES (A_BYTES + B_BYTES)  // 36864

typedef __attribute__((ext_vector_type(4))) int i32x4;

__device__ __forceinline__ void gl_lds16(const void* g, void* lds) {
    __builtin_amdgcn_global_load_lds(
        (const __attribute__((address_space(1))) unsigned int*)g,
        (__attribute__((address_space(3))) unsigned int*)lds, 16, 0, 0);
}

// ---------- kernel 1a: attr -> int8 (per-row scale), plus inv-norm & score scale ----
__global__ __launch_bounds__(256) void quant_attr(
    const float* __restrict__ in, signed char* __restrict__ q,
    float* __restrict__ sattr, float* __restrict__ inv) {
    const int w = threadIdx.x >> 6, l = threadIdx.x & 63;
    const int row = blockIdx.x * 4 + w;
    const float4* p = reinterpret_cast<const float4*>(in) + (size_t)row * (FEAT / 4);
    const float4 v0 = p[l * 2], v1 = p[l * 2 + 1];
    float ss = v0.x * v0.x + v0.y * v0.y + v0.z * v0.z + v0.w * v0.w +
               v1.x * v1.x + v1.y * v1.y + v1.z * v1.z + v1.w * v1.w;
    float mx = fmaxf(fmaxf(fmaxf(fabsf(v0.x), fabsf(v0.y)), fmaxf(fabsf(v0.z), fabsf(v0.w))),
                     fmaxf(fmaxf(fabsf(v1.x), fabsf(v1.y)), fmaxf(fabsf(v1.z), fabsf(v1.w))));
#pragma unroll
    for (int m = 1; m < 64; m <<= 1) {
        ss += __shfl_xor(ss, m);
        mx = fmaxf(mx, __shfl_xor(mx, m));
    }
    mx = fmaxf(mx, 1e-20f);
    const float iv = 1.0f / sqrtf(ss);
    const float qs = 127.0f / mx;
    const int q0 = __float2int_rn(v0.x * qs), q1 = __float2int_rn(v0.y * qs);
    const int q2 = __float2int_rn(v0.z * qs), q3 = __float2int_rn(v0.w * qs);
    const int q4 = __float2int_rn(v1.x * qs), q5 = __float2int_rn(v1.y * qs);
    const int q6 = __float2int_rn(v1.z * qs), q7 = __float2int_rn(v1.w * qs);
    int2 st;
    st.x = (q0 & 255) | ((q1 & 255) << 8) | ((q2 & 255) << 16) | ((unsigned)(q3 & 255) << 24);
    st.y = (q4 & 255) | ((q5 & 255) << 8) | ((q6 & 255) << 16) | ((unsigned)(q7 & 255) << 24);
    *reinterpret_cast<int2*>(q + (size_t)row * FEAT + l * 8) = st;
    if (l == 0) {
        inv[row] = iv;
        sattr[row] = mx * iv * (1.0f / 127.0f);  // score = idot * sattr (img scale cancels)
    }
}

// ---------- kernel 1b: img -> int8 (per-row scale, scale not needed for ranking) ----
__global__ __launch_bounds__(256) void quant_img(
    const float* __restrict__ in, signed char* __restrict__ q) {
    const int w = threadIdx.x >> 6, l = threadIdx.x & 63;
    const int row = blockIdx.x * 4 + w;
    const float4* p = reinterpret_cast<const float4*>(in) + (size_t)row * (FEAT / 4);
    const float4 v0 = p[l * 2], v1 = p[l * 2 + 1];
    float mx = fmaxf(fmaxf(fmaxf(fabsf(v0.x), fabsf(v0.y)), fmaxf(fabsf(v0.z), fabsf(v0.w))),
                     fmaxf(fmaxf(fabsf(v1.x), fabsf(v1.y)), fmaxf(fabsf(v1.z), fabsf(v1.w))));
#pragma unroll
    for (int m = 1; m < 64; m <<= 1) mx = fmaxf(mx, __shfl_xor(mx, m));
    mx = fmaxf(mx, 1e-20f);
    const float qs = 127.0f / mx;
    const int q0 = __float2int_rn(v0.x * qs), q1 = __float2int_rn(v0.y * qs);
    const int q2 = __float2int_rn(v0.z * qs), q3 = __float2int_rn(v0.w * qs);
    const int q4 = __float2int_rn(v1.x * qs), q5 = __float2int_rn(v1.y * qs);
    const int q6 = __float2int_rn(v1.z * qs), q7 = __float2int_rn(v1.w * qs);
    int2 st;
    st.x = (q0 & 255) | ((q1 & 255) << 8) | ((q2 & 255) << 16) | ((unsigned)(q3 & 255) << 24);
    st.y = (q4 & 255) | ((q5 & 255) << 8) | ((q6 & 255) << 16) | ((unsigned)(q7 & 255) << 24);
    *reinterpret_cast<int2*>(q + (size_t)row * FEAT + l * 8) = st;
}

// ---------- kernel 2: i8 MFMA coarse scoring (attr x img), reg-local top-5 ----------
// Block: 512 attrs x 64 imgs, 8 waves M-split (wave tile 64x64, acc[4][4]).
// LDS dbuf 72KB + 2KB scales; counted vmcnt; 16 waves/CU target.
__global__ __launch_bounds__(512, 4) void coarse_kernel(
    const signed char* __restrict__ attrQ, const signed char* __restrict__ imgQ,
    const float* __restrict__ sattr, unsigned* __restrict__ cand,
    int nablk, int niblk) {
    __shared__ char lds[2][BUF_BYTES];
    __shared__ float ssc[ABLK];
    const int tid = threadIdx.x;

    // bijective XCD swizzle (gridDim.x % 8 == 0); iblock fastest within XCD
    const int cpx = gridDim.x >> 3;
    const int wg = ((int)blockIdx.x & 7) * cpx + ((int)blockIdx.x >> 3);
    const int ablock = wg / niblk;
    const int iblock = wg % niblk;

    const int w = tid >> 6, l = tid & 63;
    const int lrow = l & 15, lg = l >> 4;

    // ---- staging geometry (pre-swizzled source; linear gl_lds dest) ----
    // A: thread covers slots tid + i*512 (i<4); row = slot>>2 = (tid>>2)+i*128,
    // granule = tid&3. sw(row) = (row ^ (row>>2)) & 3 invariant across i.
    const int arow0 = tid >> 2, ag = tid & 3;
    const int asw = (arow0 ^ (arow0 >> 2)) & 3;
    const signed char* asrc0 =
        attrQ + (size_t)(ablock * ABLK + arow0) * FEAT + ((ag ^ asw) << 4);
    // B: threads 0..255 cover slot tid; row = tid>>2 (0..63), granule = tid&3.
    const int brow = (tid >> 2) & 63, bg = tid & 3;
    const int bsw = (brow ^ (brow >> 2)) & 3;
    const signed char* bsrc0 =
        imgQ + (size_t)(iblock * IBLK + brow) * FEAT + ((bg ^ bsw) << 4);

    // ---- fragment read offsets (swizzled) ----
    int a_off[4], b_off[4];
#pragma unroll
    for (int m = 0; m < 4; ++m) {
        const int r = w * 64 + m * 16 + lrow;
        a_off[m] = r * BKT + ((lg ^ ((r ^ (r >> 2)) & 3)) << 4);
    }
#pragma unroll
    for (int n = 0; n < 4; ++n) {
        const int r = n * 16 + lrow;
        b_off[n] = A_BYTES + r * BKT + ((lg ^ ((r ^ (r >> 2)) & 3)) << 4);
    }

    // stage per-attr score scales (512 floats = 2KB) via waves 0-1
    if (tid < 128) gl_lds16(sattr + (size_t)ablock * ABLK + tid * 4, &ssc[tid * 4]);

    i32x4 acc[4][4];
#pragma unroll
    for (int m = 0; m < 4; ++m)
#pragma unroll
        for (int n = 0; n < 4; ++n) acc[m][n] = (i32x4){0, 0, 0, 0};

#define STAGE(bufi, kt)                                                     \
    {                                                                       \
        const signed char* as_ = asrc0 + (kt) * BKT;                        \
        char* d_ = &lds[bufi][tid * 16];                                    \
        _Pragma("unroll")                                                   \
        for (int i_ = 0; i_ < 4; ++i_)                                      \
            gl_lds16(as_ + (size_t)i_ * 128 * FEAT, d_ + i_ * 8192);        \
        if (tid < 256)                                                      \
            gl_lds16(bsrc0 + (kt) * BKT, &lds[bufi][A_BYTES + tid * 16]);   \
    }

#define COMPUTE(bufi)                                                       \
    {                                                                       \
        i32x4 aF[4], bF[4];                                                 \
        _Pragma("unroll")                                                   \
        for (int m_ = 0; m_ < 4; ++m_)                                      \
            aF[m_] = *reinterpret_cast<const i32x4*>(&lds[bufi][a_off[m_]]);\
        _Pragma("unroll")                                                   \
        for (int n_ = 0; n_ < 4; ++n_)                                      \
            bF[n_] = *reinterpret_cast<const i32x4*>(&lds[bufi][b_off[n_]]);\
        __builtin_amdgcn_s_setprio(1);                                      \
        _Pragma("unroll")                                                   \
        for (int m_ = 0; m_ < 4; ++m_)                                      \
            _Pragma("unroll")                                               \
            for (int n_ = 0; n_ < 4; ++n_)                                  \
                acc[m_][n_] = __builtin_amdgcn_mfma_i32_16x16x64_i8(        \
                    aF[m_], bF[n_], acc[m_][n_], 0, 0, 0);                  \
        __builtin_amdgcn_s_setprio(0);                                      \
    }

    STAGE(0, 0);
#pragma unroll 1
    for (int kt = 0; kt < NKT; ++kt) {
        const int cur = kt & 1;
        if (kt < NKT - 1) STAGE(cur ^ 1, kt + 1);
        __builtin_amdgcn_sched_barrier(0);
        if (kt < NKT - 1) {
            if (tid < 256) {
                asm volatile("s_waitcnt vmcnt(5)" ::: "memory");
            } else {
                asm volatile("s_waitcnt vmcnt(4)" ::: "memory");
            }
        } else {
            asm volatile("s_waitcnt vmcnt(0)" ::: "memory");
        }
        __builtin_amdgcn_s_barrier();
        __builtin_amdgcn_sched_barrier(0);
        COMPUTE(cur);
        __builtin_amdgcn_sched_barrier(0);
        __builtin_amdgcn_s_barrier();
        __builtin_amdgcn_sched_barrier(0);
    }
#undef STAGE
#undef COMPUTE

    // ---- fold acc -> packed per-lane top5 per n-group (register-local) ----
    // R4-proven sign-flip pack: full fp32 monotone bijection, no range assumption.
    // (Per-img quant scale is a positive per-column factor -> per-column ranking
    //  is invariant; do NOT use bias+clamp packs, they saturate: R5 lesson.)
    unsigned tops[4][TOPK];
#pragma unroll
    for (int n = 0; n < 4; ++n)
#pragma unroll
        for (int j = 0; j < TOPK; ++j) tops[n][j] = 0u;

#pragma unroll
    for (int m = 0; m < 4; ++m)
#pragma unroll
        for (int r = 0; r < 4; ++r) {
            const int rowl = w * 64 + m * 16 + lg * 4 + r;  // local attr 0..511
            const float sc = ssc[rowl];
            const unsigned idxc = 2047u - (unsigned)rowl;
#pragma unroll
            for (int n = 0; n < 4; ++n) {
                const float sf = (float)acc[m][n][r] * sc;
                unsigned u = __float_as_uint(sf);
                u = ((int)u < 0) ? ~u : (u | 0x80000000u);
                const unsigned pkd = (u & 0xFFFFF800u) | idxc;
                if (pkd > tops[n][TOPK - 1]) {
                    tops[n][TOPK - 1] = pkd;
#pragma unroll
                    for (int x = TOPK - 1; x > 0; --x)
                        if (tops[n][x] > tops[n][x - 1]) {
                            const unsigned t_ = tops[n][x];
                            tops[n][x] = tops[n][x - 1];
                            tops[n][x - 1] = t_;
                        }
                }
            }
        }

    // intra-wave merge: lanes l, l^16, l^32, l^48 share img col = n*16 + (l&15)
#pragma unroll
    for (int n = 0; n < 4; ++n) {
        unsigned mg[TOPK];
#pragma unroll
        for (int msk = 16; msk <= 32; msk <<= 1) {
#pragma unroll
            for (int j = 0; j < TOPK; ++j) {
                const unsigned o = __shfl_xor(tops[n][TOPK - 1 - j], msk);
                mg[j] = o > tops[n][j] ? o : tops[n][j];
            }
#define CEU(a, b) { if (mg[b] > mg[a]) { unsigned t_ = mg[a]; mg[a] = mg[b]; mg[b] = t_; } }
            CEU(0, 1) CEU(1, 2) CEU(2, 3) CEU(3, 4)
            CEU(0, 1) CEU(1, 2) CEU(2, 3)
            CEU(0, 1) CEU(1, 2)
            CEU(0, 1)
#undef CEU
#pragma unroll
            for (int j = 0; j < TOPK; ++j) tops[n][j] = mg[j];
        }
    }

    __syncthreads();  // K-loop LDS idle; reuse buffer 0 as scratch
    unsigned* scratch = (unsigned*)&lds[0][0];  // [8 waves][64 imgs][5]
    if (l < 16) {
#pragma unroll
        for (int n = 0; n < 4; ++n)
#pragma unroll
            for (int j = 0; j < TOPK; ++j)
                scratch[(w * 64 + n * 16 + l) * TOPK + j] = tops[n][j];
    }
    __syncthreads();
    if (tid < IBLK) {
        unsigned best[TOPK] = {0u, 0u, 0u, 0u, 0u};
#pragma unroll
        for (int w2 = 0; w2 < 8; ++w2)
#pragma unroll
            for (int j = 0; j < TOPK; ++j) {
                const unsigned pkd = scratch[(w2 * 64 + tid) * TOPK + j];
                if (pkd > best[TOPK - 1]) {
                    best[TOPK - 1] = pkd;
#pragma unroll
                    for (int x = TOPK - 1; x > 0; --x)
                        if (best[x] > best[x - 1]) {
                            const unsigned t_ = best[x];
                            best[x] = best[x - 1]; best[x - 1] = t_;
                        }
                }
            }
        const size_t base = ((size_t)(iblock * IBLK + tid) * nablk + ablock) * TOPK;
#pragma unroll
        for (int j = 0; j < TOPK; ++j) cand[base + j] = best[j];
    }
}

// ---------- kernel 3: per-img merge of nablk*5 packed candidates -> top-16 ----------
__global__ __launch_bounds__(64) void select16_kernel(
    const unsigned* __restrict__ cand, int* __restrict__ sel, int nablk) {
    const int row = blockIdx.x;
    const int l = threadIdx.x;
    const int ncand = nablk * TOPK;  // 625
    const unsigned* cr = cand + (size_t)row * ncand;
    unsigned p[10]; int c[10];
#pragma unroll
    for (int j = 0; j < 10; ++j) {
        const int slot = l * 10 + j;
        if (slot < ncand) {
            const unsigned v = cr[slot];
            p[j] = v;
            c[j] = (slot / TOPK) * ABLK + (2047 - (int)(v & 0x7FFu));
        } else { p[j] = 0u; c[j] = 0x7fffffff; }
    }
    int* out = sel + (size_t)row * NSEL;
    for (int r = 0; r < NSEL; ++r) {
        unsigned bp = 0u; int bc = 0x7fffffff;
#pragma unroll
        for (int j = 0; j < 10; ++j)
            if (p[j] > bp || (p[j] == bp && c[j] < bc)) { bp = p[j]; bc = c[j]; }
#pragma unroll
        for (int m = 1; m < 64; m <<= 1) {
            const unsigned op = __shfl_xor(bp, m);
            const int oc = __shfl_xor(bc, m);
            if (op > bp || (op == bp && oc < bc)) { bp = op; bc = oc; }
        }
        if (l == 0) out[r] = bc;
#pragma unroll
        for (int j = 0; j < 10; ++j)
            if (p[j] == bp && c[j] == bc) { p[j] = 0u; c[j] = 0x7fffffff; }
    }
}

// ---------- kernel 4: exact fp32 rescore of 16 candidates -> final top-5 ----------
__global__ __launch_bounds__(256) void rescore_kernel(
    const float* __restrict__ img, const float* __restrict__ attr,
    const float* __restrict__ inv, const int* __restrict__ sel,
    float* __restrict__ out_scores, int* __restrict__ final_i) {
    __shared__ float s_sc[NSEL];
    const int row = blockIdx.x;
    const int w = threadIdx.x >> 6, l = threadIdx.x & 63;
    const float4* ip = reinterpret_cast<const float4*>(img) + (size_t)row * (FEAT / 4);
    const float4 a0 = ip[l * 2], a1 = ip[l * 2 + 1];
#pragma unroll
    for (int q = 0; q < 4; ++q) {
        const int slot = w * 4 + q;
        const int ci = sel[(size_t)row * NSEL + slot];
        const float4* ap = reinterpret_cast<const float4*>(attr) + (size_t)ci * (FEAT / 4);
        const float4 b0 = ap[l * 2], b1 = ap[l * 2 + 1];
        float d = a0.x * b0.x + a0.y * b0.y + a0.z * b0.z + a0.w * b0.w +
                  a1.x * b1.x + a1.y * b1.y + a1.z * b1.z + a1.w * b1.w;
#pragma unroll
        for (int m = 1; m < 64; m <<= 1) d += __shfl_xor(d, m);
        if (l == 0) s_sc[slot] = d * inv[ci];
    }
    __syncthreads();
    if (threadIdx.x == 0) {
        float ts[TOPK]; int ti[TOPK];
#pragma unroll
        for (int j = 0; j < TOPK; ++j) { ts[j] = -FLT_MAX; ti[j] = 0x7fffffff; }
        for (int e = 0; e < NSEL; ++e) {
            const float sv = s_sc[e];
            const int iv = sel[(size_t)row * NSEL + e];
            if (sv > ts[4] || (sv == ts[4] && iv < ti[4])) {
                ts[4] = sv; ti[4] = iv;
#pragma unroll
                for (int x = 4; x > 0; --x)
                    if (ts[x] > ts[x - 1] || (ts[x] == ts[x - 1] && ti[x] < ti[x - 1])) {
                        const float tf = ts[x]; ts[x] = ts[x - 1]; ts[x - 1] = tf;
                        const int td = ti[x]; ti[x] = ti[x - 1]; ti[x - 1] = td;
                    }
            }
        }
#pragma unroll
        for (int j = 0; j < TOPK; ++j) {
            out_scores[(size_t)row * TOPK + j] = ts[j];
            final_i[(size_t)row * TOPK + j] = ti[j];
        }
    }
}

// ---------- kernel 5: gather normalized winners ----------
__global__ __launch_bounds__(128) void gather_kernel(
    const float* __restrict__ attr, const float* __restrict__ inv,
    const int* __restrict__ final_i, float* __restrict__ out0) {
    const int pair = blockIdx.x;  // b*TOPK + k
    const int fi = final_i[pair];
    const float sc = inv[fi];
    const float4 v =
        reinterpret_cast<const float4*>(attr)[(size_t)fi * (FEAT / 4) + threadIdx.x];
    float4 o;
    o.x = v.x * sc; o.y = v.y * sc; o.z = v.z * sc; o.w = v.w * sc;
    reinterpret_cast<float4*>(out0)[(size_t)pair * (FEAT / 4) + threadIdx.x] = o;
}

extern "C" void kernel_launch(void* const* d_in, const int* in_sizes, int n_in,
                              void* d_out, int out_size, void* d_ws, size_t ws_size,
                              hipStream_t stream) {
    const float* img = (const float*)d_in[0];
    const float* attr = (const float*)d_in[1];
    const int batch = in_sizes[0] / FEAT;  // 4096
    const int nattr = in_sizes[1] / FEAT;  // 64000
    const int nablk = nattr / ABLK;        // 125
    const int niblk = batch / IBLK;        // 64

    // workspace layout (~45 MB, 16B-aligned segments)
    char* ws = (char*)d_ws;
    signed char* attrQ = (signed char*)ws; ws += (size_t)nattr * FEAT;
    signed char* imgQ = (signed char*)ws;  ws += (size_t)batch * FEAT;
    float* sattr = (float*)ws;             ws += (size_t)nattr * 4;
    float* inv = (float*)ws;               ws += (size_t)nattr * 4;
    unsigned* cand = (unsigned*)ws;        ws += (size_t)batch * nablk * TOPK * 4;
    int* sel = (int*)ws;                   ws += (size_t)batch * NSEL * 4;
    int* final_i = (int*)ws;               ws += (size_t)batch * TOPK * 4;

    float* out0 = (float*)d_out;                             // [batch][5][512]
    float* out_scores = out0 + (size_t)batch * TOPK * FEAT;  // [batch][5]

    quant_attr<<<nattr / 4, 256, 0, stream>>>(attr, attrQ, sattr, inv);
    quant_img<<<batch / 4, 256, 0, stream>>>(img, imgQ);
    coarse_kernel<<<nablk * niblk, 512, 0, stream>>>(attrQ, imgQ, sattr, cand,
                                                     nablk, niblk);
    select16_kernel<<<batch, 64, 0, stream>>>(cand, sel, nablk);
    rescore_kernel<<<batch, 256, 0, stream>>>(img, attr, inv, sel, out_scores, final_i);
    gather_kernel<<<batch * TOPK, 128, 0, stream>>>(attr, inv, final_i, out0);
}